// Round 11
// baseline (10.241 us; speedup 1.0000x reference)
//
#include <hip/hip_runtime.h>
#include <math.h>

#define H_DIM 1024
#define N_DIM 64
#define L_DIM 2048
#define NT 256
#define SAU 68   // A' row stride in uints: 64 + 4 pad  (=136 bf16, 272B)

typedef float    f32x4  __attribute__((ext_vector_type(4)));
typedef short    bf16x8 __attribute__((ext_vector_type(8)));

__device__ __forceinline__ float exp2_hw(float x) {
    float o; asm("v_exp_f32 %0, %1" : "=v"(o) : "v"(x)); return o;
}
__device__ __forceinline__ float log2_hw(float x) {
    float o; asm("v_log_f32 %0, %1" : "=v"(o) : "v"(x)); return o;
}
// packs (lo, hi) -> one u32 of two bf16 (lo in low 16)
__device__ __forceinline__ unsigned cvt_pk_bf16(float lo, float hi) {
    unsigned r; asm("v_cvt_pk_bf16_f32 %0, %1, %2" : "=v"(r) : "v"(lo), "v"(hi));
    return r;
}
__device__ __forceinline__ float2 cmul(float2 x, float2 y) {
    return make_float2(fmaf(x.x, y.x, -(x.y * y.y)),
                       fmaf(x.x, y.y,  x.y * y.x));
}
__device__ __forceinline__ float2 csq(float2 x) {
    return make_float2(fmaf(x.x, x.x, -(x.y * x.y)), 2.0f * x.x * x.y);
}

// K[h][32*l1+l0] = sum_k A'[l1][k] * B'[k][l0], k = 0..127:
//   A'[l1][2n] = Re(U)[n][l1], A'[l1][2n+1] = -Im(U)[n][l1]  (U = w * a^(32 l1))
//   B'[2n][l0] = Re(V)[n][l0], B'[2n+1][l0] =  Im(V)[n][l0]  (V = a^l0)
// Phase 0 (t<64): per-n params -> LDS {U-starts w*a^(512q), a32, V-starts a^(8q), a}
// Phase 1 (all): chain gen, one cvt_pk + one ds_write_b32 per complex value.
//   A' row-major [l1][k]; B' in swizzled MFMA fragment slots
//   (g*32 + (l0 ^ (g&7)))*4 + ((k&7)>>1)  — writes 2-way/bank-free, reads one
//   contiguous 16B slot per lane (same XOR both sides).
// Phase 2: 8 MFMAs (K=128), measured C/D layout store. (Identical to R10.)
__global__ __launch_bounds__(NT, 4)
void lssl_mfma(const float* __restrict__ Lre, const float* __restrict__ Lim,
               const float* __restrict__ Bre, const float* __restrict__ Bim,
               const float* __restrict__ Cre, const float* __restrict__ Cim,
               const float* __restrict__ Dv,  const float* __restrict__ log_dt,
               float* __restrict__ out)
{
    __shared__ __align__(16) unsigned sAp[64 * SAU];    // A' (17.4 KB)
    __shared__ __align__(16) unsigned sBp[16 * 32 * 4]; // B' (8 KB)
    __shared__ float2 sU0[4 * 64];   // U start per (q,n): w * a^(512q)
    __shared__ float2 sV0[4 * 64];   // V start per (q,n): a^(8q)
    __shared__ float2 sUst[64];      // a^32 per n
    __shared__ float2 sVst[64];      // a per n

    const int h = blockIdx.x;
    const int t = threadIdx.x;
    const int n = t & 63;
    const int q = t >> 6;          // 0..3, wave-uniform

    // ---- phase 0: per-(h,n) params, one thread per n ----
    if (t < 64) {
        const float LOG2E = 1.44269504089f, LN2 = 0.69314718056f;
        const int   idx = h * N_DIM + t;
        const float dt  = exp2_hw(log_dt[h] * LOG2E);
        const float lre = Lre[idx];
        const float lim = Lim[idx];
        const float sp  = LN2 * log2_hw(1.0f + exp2_hw(lre * LOG2E));  // softplus
        const float hr  = -0.5f * dt * sp;
        const float hi  =  0.5f * dt * lim;
        const float dr  = 1.0f - hr;             // denom = (dr, -hi)
        const float inv = 1.0f / (dr * dr + hi * hi);
        const float xr  = 1.0f + hr;
        const float2 a  = make_float2((xr * dr - hi * hi) * inv, 2.0f * hi * inv);
        const float tr  = dt * dr * inv;
        const float ti  = dt * hi * inv;
        const float br  = tr * Bre[idx] - ti * Bim[idx];   // b_bar
        const float bi  = tr * Bim[idx] + ti * Bre[idx];
        const float cre = Cre[idx], cim = Cim[idx];
        const float2 w  = make_float2(cre * br - cim * bi, // w = C*b_bar
                                      cre * bi + cim * br);

        const float2 a2   = csq(a);
        const float2 a4   = csq(a2);
        const float2 a8   = csq(a4);
        const float2 a16  = csq(a8);
        const float2 a32  = csq(a16);
        const float2 a64  = csq(a32);
        const float2 a128 = csq(a64);
        const float2 a256 = csq(a128);
        const float2 a512 = csq(a256);

        sUst[t] = a32;
        sVst[t] = a;
        float2 u = w;
        sU0[t]       = u;
        u = cmul(u, a512); sU0[64  + t] = u;
        u = cmul(u, a512); sU0[128 + t] = u;
        u = cmul(u, a512); sU0[192 + t] = u;
        sV0[t]       = make_float2(1.0f, 0.0f);
        sV0[64  + t] = a8;
        sV0[128 + t] = a16;
        sV0[192 + t] = cmul(a16, a8);
    }
    __syncthreads();

    // ---- phase 1: chain generation (starts: sU0[t], sV0[t] since t = q*64+n) ----
    {
        float2 s = sU0[t];
        const float2 stU = sUst[n];
        unsigned* ap = &sAp[(q * 16) * SAU + n];
#pragma unroll
        for (int j = 0; j < 16; ++j) {
            ap[j * SAU] = cvt_pk_bf16(s.x, -s.y);
            s = cmul(s, stU);
        }

        float2 v = sV0[t];
        const float2 stV = sVst[n];
        const int g   = n >> 2;
        const int gs4 = (g & 7) << 2;
        const int vb  = g * 128 + 32 * q + (n & 3);
#pragma unroll
        for (int i = 0; i < 8; ++i) {
            sBp[vb + ((i << 2) ^ gs4)] = cvt_pk_bf16(v.x, v.y);
            v = cmul(v, stV);
        }
    }
    __syncthreads();

    // ---- phase 2: MFMA, wave q owns M-tile q; K=128 in 4 steps of 32 ----
    const int col = t & 15;
    const int grp = (t & 63) >> 4;
    f32x4 acc0 = {0.f, 0.f, 0.f, 0.f};
    f32x4 acc1 = {0.f, 0.f, 0.f, 0.f};

#pragma unroll
    for (int ks = 0; ks < 4; ++ks) {
        const int gg  = ks * 4 + grp;                 // k-hat: gg*8 + j
        const bf16x8 af = *(const bf16x8*)&sAp[(q * 16 + col) * SAU + ks * 16 + grp * 4];
        const int b0i = (gg * 32 + (col ^ (gg & 7))) * 4;
        const bf16x8 b0 = *(const bf16x8*)&sBp[b0i];
        const bf16x8 b1 = *(const bf16x8*)&sBp[b0i + 64];   // l0 = col+16
        acc0 = __builtin_amdgcn_mfma_f32_16x16x32_bf16(af, b0, acc0, 0, 0, 0);
        acc1 = __builtin_amdgcn_mfma_f32_16x16x32_bf16(af, b1, acc1, 0, 0, 0);
    }

    // ---- store: D row=(lane>>4)*4+reg, col=lane&15 (measured C/D layout) ----
    float* o = out + (size_t)h * L_DIM;
#pragma unroll
    for (int r = 0; r < 4; ++r) {
        const int row = q * 16 + grp * 4 + r;         // l1
        o[row * 32 + col]      = acc0[r];
        o[row * 32 + 16 + col] = acc1[r];
    }

    if (t == 0) out[(size_t)H_DIM * L_DIM + h] = Dv[h];
}

extern "C" void kernel_launch(void* const* d_in, const int* in_sizes, int n_in,
                              void* d_out, int out_size, void* d_ws, size_t ws_size,
                              hipStream_t stream) {
    const float* Lre   = (const float*)d_in[0];
    const float* Lim   = (const float*)d_in[1];
    const float* Bre   = (const float*)d_in[2];
    const float* Bim   = (const float*)d_in[3];
    const float* Cre   = (const float*)d_in[4];
    const float* Cim   = (const float*)d_in[5];
    const float* Dv    = (const float*)d_in[6];
    const float* logdt = (const float*)d_in[7];
    float* out = (float*)d_out;

    lssl_mfma<<<dim3(H_DIM), dim3(NT), 0, stream>>>(
        Lre, Lim, Bre, Bim, Cre, Cim, Dv, logdt, out);
}